// Round 10
// baseline (306.333 us; speedup 1.0000x reference)
//
#include <hip/hip_runtime.h>

#define B_  8
#define S_  4096
#define D_  768
#define H_  12
#define M_  (B_ * S_)      // 32768
#define NQKV_ 2304         // 3*D
#define NTILES 12          // 768 / 64

typedef unsigned short u16;
typedef __attribute__((ext_vector_type(4))) float  f32x4;
typedef __attribute__((ext_vector_type(8))) __bf16 bf16x8;
typedef __attribute__((ext_vector_type(4))) u16    u16x4;

#define GAS __attribute__((address_space(1)))
#define LAS __attribute__((address_space(3)))

__device__ __forceinline__ u16 f2bf(float f) {
    unsigned u = __float_as_uint(f);
    u += 0x7FFF + ((u >> 16) & 1);          // round-to-nearest-even
    return (u16)(u >> 16);
}
__device__ __forceinline__ float bf2f(u16 h) {
    return __uint_as_float(((unsigned)h) << 16);
}

__device__ __forceinline__ void gload_lds16(const void* g, void* l) {
    __builtin_amdgcn_global_load_lds((const GAS void*)g, (LAS void*)l, 16, 0, 0);
}

// bijective XCD swizzle (nwg % 8 == 0): each XCD gets a contiguous work chunk
__device__ __forceinline__ int xcd_swz(int bid, int nwg) {
    return (bid & 7) * (nwg >> 3) + (bid >> 3);
}

// ---------------- cast x (f32 -> bf16) ----------------
__global__ __launch_bounds__(256) void castx_kernel(const float* __restrict__ x,
                                                    u16* __restrict__ xb) {
    const int i = blockIdx.x * 256 + threadIdx.x;
    const float4 v = ((const float4*)x)[i];
    u16x4 o;
    o.x = f2bf(v.x); o.y = f2bf(v.y); o.z = f2bf(v.z); o.w = f2bf(v.w);
    ((u16x4*)xb)[i] = o;
}

// ---------------- weight transpose+cast: W[k][n] f32 -> Wb[n][k] bf16 ----------------
__global__ __launch_bounds__(256) void wtrans_kernel(const float* __restrict__ Wq,
                                                     const float* __restrict__ Wk,
                                                     const float* __restrict__ Wv,
                                                     const float* __restrict__ Wo,
                                                     u16* __restrict__ Wb) {
    const float* W = (blockIdx.z == 0) ? Wq : (blockIdx.z == 1) ? Wk
                   : (blockIdx.z == 2) ? Wv : Wo;
    u16* O = Wb + (size_t)blockIdx.z * D_ * D_;
    __shared__ float tile[32][33];
    const int tx = threadIdx.x & 31, ty = threadIdx.x >> 5;  // 32x8
    const int k0 = blockIdx.y * 32, n0 = blockIdx.x * 32;
#pragma unroll
    for (int j = 0; j < 4; j++)
        tile[ty + j * 8][tx] = W[(size_t)(k0 + ty + j * 8) * D_ + n0 + tx];
    __syncthreads();
#pragma unroll
    for (int j = 0; j < 4; j++)
        O[(size_t)(n0 + ty + j * 8) * D_ + k0 + tx] = f2bf(tile[tx][ty + j * 8]);
}

// ============ 128x256 TRI-BUFFER k-half-pipelined bf16 MFMA GEMM ============
// 512 threads = 8 waves (2M x 4N), per-wave C = 64x64 (acc 64 AGPR), BK=64.
// LDS 72 KiB: A regions r=0..2 at r*8KiB (128 rows x 32 cols, 64B rows);
//             B regions r=0..2 at 24576 + r*16KiB (256 rows x 32 cols).
// 24 phases (12 K-tiles x 2 k-halves). Phase p:
//   { read 8 b128 from region p%3;
//     stage 3 gloads for phase p+2 into region (p+2)%3 (tile wraps at tail);
//     vmcnt(3); s_barrier; lgkmcnt(0); setprio1; 16 MFMA; setprio0; s_barrier }
// Ledger (per wave): at p's vmcnt, outstanding = S(p+1)+S(p+2) = 6 ->
//   retires S(p+1); barrier after the vmcnt makes ALL waves' slices resident
//   before phase p+1's reads (cross-wave RAW safe).  Distance-1 prefetch with
//   counted vmcnt is IMPOSSIBLE (R9 lesson: vmcnt(3) with 3 outstanding is a
//   no-op); distance-2 requires the 3rd region (WAR: region (p+2)%3 last read
//   in p-1, fully drained before p-1's trailing barrier; stage issues after).
// Prologue: S(0),S(1); vmcnt(3) retires S(0); barrier.  Tail stages wrap to
//   tile 0 (uniform ledger, data never read); vmcnt(0) drain after loop.
// Swizzle: 16B-slot s of row R holds global chunk s ^ f(R), f(R)=(R^(R>>2))&3;
//   f(R+16)==f(R), msub/nsub-invariant -> one per-lane constant for both
//   staging source and ds_read slot. 2-way conflict max (free).
// Occupancy: <=128 regs (launch_bounds(512,4)) + 72 KiB -> 2 blocks/CU.

#define MFMA16(AF, BF)                                                       \
    __builtin_amdgcn_s_setprio(1);                                           \
    _Pragma("unroll") for (int mi = 0; mi < 4; ++mi)                         \
        _Pragma("unroll") for (int ni = 0; ni < 4; ++ni)                     \
            acc[mi][ni] = __builtin_amdgcn_mfma_f32_16x16x32_bf16(           \
                AF[mi], BF[ni], acc[mi][ni], 0, 0, 0);                       \
    __builtin_amdgcn_s_setprio(0)

#define RD(p, imm) (*(const bf16x8*)((p) + (imm)))

template <int MODE>
__global__ __launch_bounds__(512, 4) void gemmf_kernel(
    const u16* __restrict__ A, const u16* __restrict__ Wb,
    const float* __restrict__ b0, const float* __restrict__ b1,
    const float* __restrict__ b2,
    u16* __restrict__ outb, const u16* __restrict__ xres) {
    extern __shared__ char lds[];    // 73728 B

    const int t = threadIdx.x;
    const int w = t >> 6, l = t & 63;
    const int wm = w >> 2, wn = w & 3;

    const int NTN = (MODE == 0) ? 9 : 3;
    const int work = xcd_swz(blockIdx.x, gridDim.x);
    const int mt = work / NTN, nt = work % NTN;
    const int m0 = mt * 128;
    const int n0 = nt * 256;
    const int widx = (MODE == 0) ? (n0 / D_) : 3;
    const int n0w = n0 - ((MODE == 0) ? widx * D_ : 0);

    // ---- staging lane geometry (pre-swizzled global source) ----
    const int sc   = l & 3;                      // 16B chunk within 64B row
    const int srA  = w * 16 + (l >> 2);          // A row 0..127
    const int srB  = w * 32 + (l >> 2);          // B row (call 1); call 2 = +16
    const int fA   = (srA ^ (srA >> 2)) & 3;
    const int fB   = (srB ^ (srB >> 2)) & 3;     // f(srB+16) == f(srB)
    const u16* AsrcB = A + (size_t)(m0 + srA) * D_ + (sc ^ fA) * 8;
    const u16* BsrcB = Wb + (size_t)widx * (D_ * D_)
                          + (size_t)(n0w + srB) * D_ + (sc ^ fB) * 8;
    char* const dstA = lds + w * 1024;            // + region*8192
    char* const dstB = lds + 24576 + w * 2048;    // + region*16384 (+1024 call2)

    // ---- ds_read geometry (swizzled slot) ----
    const int fr   = l & 15;
    const int slot = (l >> 4) ^ ((fr ^ (fr >> 2)) & 3);
    const char* aBase = lds + (wm * 64 + fr) * 64 + slot * 16;          // +rg*8192 + mi*1024
    const char* bBase = lds + 24576 + (wn * 64 + fr) * 64 + slot * 16;  // +rg*16384 + ni*1024

    f32x4 acc[4][4];
#pragma unroll
    for (int i = 0; i < 4; i++)
#pragma unroll
        for (int j = 0; j < 4; j++) acc[i][j] = (f32x4){0.f, 0.f, 0.f, 0.f};

    // ---- prologue: S(0) -> region 0 (tile0 kh0), S(1) -> region 1 (tile0 kh1) ----
    gload_lds16(AsrcB, dstA);
    gload_lds16(BsrcB, dstB);
    gload_lds16(BsrcB + 16 * D_, dstB + 1024);
    gload_lds16(AsrcB + 32, dstA + 8192);
    gload_lds16(BsrcB + 32, dstB + 16384);
    gload_lds16(BsrcB + 32 + 16 * D_, dstB + 16384 + 1024);
    __builtin_amdgcn_sched_barrier(0);
    asm volatile("s_waitcnt vmcnt(3)" ::: "memory");   // retire S(0)
    __builtin_amdgcn_s_barrier();
    __builtin_amdgcn_sched_barrier(0);

#pragma unroll
    for (int p = 0; p < 2 * NTILES; ++p) {
        const int rg = p % 3;                    // region read this phase
        const int sg = (p + 2) % 3;              // region staged (for phase p+2)
        const int Xs = (p + 2) >> 1;
        const int sX = (Xs >= NTILES) ? 0 : Xs;  // wrapped tile at tail
        const int soff = sX * 64 + (p & 1) * 32; // kh(p+2) == kh(p)

        // reads for phase p (region rg resident: S(p) retired at p-1's vmcnt)
        bf16x8 Af[4], Bf[4];
#pragma unroll
        for (int i = 0; i < 4; ++i)
            Af[i] = RD(aBase, rg * 8192 + i * 1024);
#pragma unroll
        for (int n = 0; n < 4; ++n)
            Bf[n] = RD(bBase, rg * 16384 + n * 1024);

        // stage S(p+2) into region sg (3 gloads)
        gload_lds16(AsrcB + soff, dstA + sg * 8192);
        gload_lds16(BsrcB + soff, dstB + sg * 16384);
        gload_lds16(BsrcB + soff + 16 * D_, dstB + sg * 16384 + 1024);

        __builtin_amdgcn_sched_barrier(0);
        asm volatile("s_waitcnt vmcnt(3)" ::: "memory");   // retire S(p+1)
        __builtin_amdgcn_s_barrier();
        asm volatile("s_waitcnt lgkmcnt(0)" ::: "memory");
        __builtin_amdgcn_sched_barrier(0);

        MFMA16(Af, Bf);

        __builtin_amdgcn_sched_barrier(0);
        __builtin_amdgcn_s_barrier();
        __builtin_amdgcn_sched_barrier(0);
    }
    asm volatile("s_waitcnt vmcnt(0)" ::: "memory");   // drain wrapped stages

    // ---- epilogue ----
    const int crow0 = m0 + wm * 64 + ((l >> 4) << 2);
    const int ccol0 = n0 + wn * 64 + fr;
    if (MODE == 0) {
        const float* bias = (widx == 0) ? b0 : (widx == 1) ? b1 : b2;
        const int bcol0 = ccol0 - widx * D_;
#pragma unroll
        for (int mi = 0; mi < 4; ++mi)
#pragma unroll
            for (int ni = 0; ni < 4; ++ni) {
                const float bv = bias[bcol0 + ni * 16];
#pragma unroll
                for (int r = 0; r < 4; ++r)
                    outb[(size_t)(crow0 + mi * 16 + r) * NQKV_ + ccol0 + ni * 16] =
                        f2bf(acc[mi][ni][r] + bv);
            }
    } else {
#pragma unroll
        for (int mi = 0; mi < 4; ++mi)
#pragma unroll
            for (int ni = 0; ni < 4; ++ni) {
                const int col = ccol0 + ni * 16;
                const float bv = b0[col];
#pragma unroll
                for (int r = 0; r < 4; ++r) {
                    const size_t idx = (size_t)(crow0 + mi * 16 + r) * D_ + col;
                    outb[idx] = f2bf(acc[mi][ni][r] + bv + bf2f(xres[idx]));
                }
            }
    }
}

// ---------------- local attention: one wave per (m, head-quad) ----------------
__global__ __launch_bounds__(256) void attn_kernel(const u16* __restrict__ QKV,
                                                   const float* __restrict__ bk,
                                                   const float* __restrict__ bv,
                                                   u16* __restrict__ att) {
    const int gw = xcd_swz(blockIdx.x, gridDim.x) * 4 + (threadIdx.x >> 6);
    const int l  = threadIdx.x & 63;
    const int hq = gw % 3;             // head-quad index
    const int m  = gw / 3;
    const int s  = m & (S_ - 1);
    const int col = hq * 256 + l * 4;
    const u16* base = QKV + (size_t)m * NQKV_;

    const u16x4 qv = *(const u16x4*)(base + col);
    float qf[4];
#pragma unroll
    for (int j = 0; j < 4; j++) qf[j] = bf2f(qv[j]);

    float sc[5];
#pragma unroll
    for (int i = 0; i < 5; i++) {
        const int sp = s + i - 2;
        float p;
        if (sp >= 0 && sp < S_) {
            const u16x4 kv = *(const u16x4*)(base + (i - 2) * NQKV_ + D_ + col);
            p = qf[0] * bf2f(kv[0]) + qf[1] * bf2f(kv[1])
              + qf[2] * bf2f(kv[2]) + qf[3] * bf2f(kv[3]);
        } else {
            const float4 kb = *(const float4*)(bk + col);
            p = qf[0] * kb.x + qf[1] * kb.y + qf[2] * kb.z + qf[3] * kb.w;
        }
#pragma unroll
        for (int off = 1; off < 16; off <<= 1) p += __shfl_xor(p, off, 64);
        sc[i] = p * 0.125f;
    }
    float mx = sc[0];
#pragma unroll
    for (int i = 1; i < 5; i++) mx = fmaxf(mx, sc[i]);
    float e[5], sum = 0.f;
#pragma unroll
    for (int i = 0; i < 5; i++) { e[i] = __expf(sc[i] - mx); sum += e[i]; }
    const float inv = 1.f / sum;

    float o[4] = {0.f, 0.f, 0.f, 0.f};
#pragma unroll
    for (int i = 0; i < 5; i++) {
        const float wgt = e[i] * inv;
        const int sp = s + i - 2;
        if (sp >= 0 && sp < S_) {
            const u16x4 vv = *(const u16x4*)(base + (i - 2) * NQKV_ + 2 * D_ + col);
#pragma unroll
            for (int j = 0; j < 4; j++) o[j] += wgt * bf2f(vv[j]);
        } else {
            const float4 vb = *(const float4*)(bv + col);
            o[0] += wgt * vb.x; o[1] += wgt * vb.y;
            o[2] += wgt * vb.z; o[3] += wgt * vb.w;
        }
    }
    u16x4 ov;
#pragma unroll
    for (int j = 0; j < 4; j++) ov[j] = f2bf(o[j]);
    *(u16x4*)(att + (size_t)m * D_ + col) = ov;
}

// ---------------- LayerNorm over rows of 768 (bf16 in, f32 out) ----------------
__global__ __launch_bounds__(256) void ln_kernel(const u16* __restrict__ Yb,
                                                 const float* __restrict__ gamma,
                                                 const float* __restrict__ beta,
                                                 float* __restrict__ out) {
    const int row = blockIdx.x;
    const u16* r = Yb + (size_t)row * D_;
    const int t = threadIdx.x;
    const float v0 = bf2f(r[t]), v1 = bf2f(r[t + 256]), v2 = bf2f(r[t + 512]);
    float s  = v0 + v1 + v2;
    float s2 = v0 * v0 + v1 * v1 + v2 * v2;
#pragma unroll
    for (int off = 32; off > 0; off >>= 1) {
        s  += __shfl_xor(s,  off, 64);
        s2 += __shfl_xor(s2, off, 64);
    }
    __shared__ float red[8];
    const int w = t >> 6, l = t & 63;
    if (l == 0) { red[w] = s; red[4 + w] = s2; }
    __syncthreads();
    s  = red[0] + red[1] + red[2] + red[3];
    s2 = red[4] + red[5] + red[6] + red[7];
    const float mu  = s * (1.f / 768.f);
    const float var = s2 * (1.f / 768.f) - mu * mu;
    const float inv = rsqrtf(var + 1e-5f);
    float* o = out + (size_t)row * D_;
    o[t]       = (v0 - mu) * inv * gamma[t]       + beta[t];
    o[t + 256] = (v1 - mu) * inv * gamma[t + 256] + beta[t + 256];
    o[t + 512] = (v2 - mu) * inv * gamma[t + 512] + beta[t + 512];
}

extern "C" void kernel_launch(void* const* d_in, const int* in_sizes, int n_in,
                              void* d_out, int out_size, void* d_ws, size_t ws_size,
                              hipStream_t stream) {
    const float* x     = (const float*)d_in[0];
    const float* Wq    = (const float*)d_in[1];
    const float* bq    = (const float*)d_in[2];
    const float* Wk    = (const float*)d_in[3];
    const float* bk    = (const float*)d_in[4];
    const float* Wv    = (const float*)d_in[5];
    const float* bv    = (const float*)d_in[6];
    const float* Wo    = (const float*)d_in[7];
    const float* bo    = (const float*)d_in[8];
    const float* gamma = (const float*)d_in[9];
    const float* beta  = (const float*)d_in[10];

    char* ws = (char*)d_ws;
    u16*   Wb  = (u16*)ws;                                  //  4,718,592 B
    u16*   xb  = (u16*)(ws + 4718592);                      // 50,331,648 B (stays live)
    u16*   QKV = (u16*)(ws + 4718592 + 50331648);           // 150,994,944 B
    u16*   yb  = QKV;                                       // reuse after attn
    u16*   att = (u16*)d_out;                               // scratch in d_out

    (void)hipFuncSetAttribute(reinterpret_cast<const void*>(&gemmf_kernel<0>),
                              hipFuncAttributeMaxDynamicSharedMemorySize, 73728);
    (void)hipFuncSetAttribute(reinterpret_cast<const void*>(&gemmf_kernel<1>),
                              hipFuncAttributeMaxDynamicSharedMemorySize, 73728);

    castx_kernel<<<(M_ * D_) / (256 * 4), 256, 0, stream>>>(x, xb);
    wtrans_kernel<<<dim3(24, 24, 4), 256, 0, stream>>>(Wq, Wk, Wv, Wo, Wb);
    gemmf_kernel<0><<<(M_ / 128) * 9, 512, 73728, stream>>>(xb, Wb, bq, bk, bv,
                                                            QKV, nullptr);
    attn_kernel<<<(M_ * 3) / 4, 256, 0, stream>>>(QKV, bk, bv, att);
    gemmf_kernel<1><<<(M_ / 128) * 3, 512, 73728, stream>>>(att, Wb, bo, nullptr, nullptr,
                                                            yb, xb);
    ln_kernel<<<M_, 256, 0, stream>>>(yb, gamma, beta, (float*)d_out);
}

// Round 11
// 294.441 us; speedup vs baseline: 1.0404x; 1.0404x over previous
//
#include <hip/hip_runtime.h>

#define B_  8
#define S_  4096
#define D_  768
#define H_  12
#define M_  (B_ * S_)      // 32768
#define NQKV_ 2304         // 3*D
#define NTILES 12          // 768 / 64

typedef unsigned short u16;
typedef __attribute__((ext_vector_type(4))) float  f32x4;
typedef __attribute__((ext_vector_type(8))) __bf16 bf16x8;
typedef __attribute__((ext_vector_type(4))) u16    u16x4;

#define GAS __attribute__((address_space(1)))
#define LAS __attribute__((address_space(3)))

__device__ __forceinline__ u16 f2bf(float f) {
    unsigned u = __float_as_uint(f);
    u += 0x7FFF + ((u >> 16) & 1);          // round-to-nearest-even
    return (u16)(u >> 16);
}
__device__ __forceinline__ float bf2f(u16 h) {
    return __uint_as_float(((unsigned)h) << 16);
}

__device__ __forceinline__ void gload_lds16(const void* g, void* l) {
    __builtin_amdgcn_global_load_lds((const GAS void*)g, (LAS void*)l, 16, 0, 0);
}

// bijective XCD swizzle (nwg % 8 == 0): each XCD gets a contiguous work chunk
__device__ __forceinline__ int xcd_swz(int bid, int nwg) {
    return (bid & 7) * (nwg >> 3) + (bid >> 3);
}

// ---------------- cast x (f32 -> bf16) ----------------
__global__ __launch_bounds__(256) void castx_kernel(const float* __restrict__ x,
                                                    u16* __restrict__ xb) {
    const int i = blockIdx.x * 256 + threadIdx.x;
    const float4 v = ((const float4*)x)[i];
    u16x4 o;
    o.x = f2bf(v.x); o.y = f2bf(v.y); o.z = f2bf(v.z); o.w = f2bf(v.w);
    ((u16x4*)xb)[i] = o;
}

// ---------------- weight transpose+cast: W[k][n] f32 -> Wb[n][k] bf16 ----------------
__global__ __launch_bounds__(256) void wtrans_kernel(const float* __restrict__ Wq,
                                                     const float* __restrict__ Wk,
                                                     const float* __restrict__ Wv,
                                                     const float* __restrict__ Wo,
                                                     u16* __restrict__ Wb) {
    const float* W = (blockIdx.z == 0) ? Wq : (blockIdx.z == 1) ? Wk
                   : (blockIdx.z == 2) ? Wv : Wo;
    u16* O = Wb + (size_t)blockIdx.z * D_ * D_;
    __shared__ float tile[32][33];
    const int tx = threadIdx.x & 31, ty = threadIdx.x >> 5;  // 32x8
    const int k0 = blockIdx.y * 32, n0 = blockIdx.x * 32;
#pragma unroll
    for (int j = 0; j < 4; j++)
        tile[ty + j * 8][tx] = W[(size_t)(k0 + ty + j * 8) * D_ + n0 + tx];
    __syncthreads();
#pragma unroll
    for (int j = 0; j < 4; j++)
        O[(size_t)(n0 + ty + j * 8) * D_ + k0 + tx] = f2bf(tile[tx][ty + j * 8]);
}

// ============ 128x128 double-buffered bf16 MFMA GEMM — 2 blocks/CU ============
// 512 threads = 8 waves (2M x 4N), per-wave C = 64x32 (acc 32 AGPR), BK=64.
// LDS 64 KiB = 2 buffers x (A 128x128B + B 128x128B), rows 128 B.
// Swizzle (VERIFIED pattern, R8/m201: 0 conflicts): LDS slot s of row R holds
//   global 16B-chunk s ^ (R&7); stage pre-swizzles the global source; reads
//   use slot = (kh*4 + (l>>4)) ^ (l&7).  msub/nsub offsets are +16 rows ->
//   (R+16)&7 invariant.
// Schedule: per K-tile { stage X+1 -> other buffer; ds_read + 16 MFMA from
//   current; __syncthreads() } — full drain each tile (no counted-vmcnt
//   ledger => no R6/R9 race class).  Stall hiding comes from 2 independent
//   blocks/CU (<=128 regs via launch_bounds(512,4), 64 KiB LDS).
// MODE 0: QKV (A=xb, out bf16 [M][2304], +bias). MODE 1: OUT (+bo+residual).

#define MFMA8(AF, BF)                                                        \
    __builtin_amdgcn_s_setprio(1);                                           \
    _Pragma("unroll") for (int mi = 0; mi < 4; ++mi)                         \
        _Pragma("unroll") for (int ni = 0; ni < 2; ++ni)                     \
            acc[mi][ni] = __builtin_amdgcn_mfma_f32_16x16x32_bf16(           \
                AF[mi], BF[ni], acc[mi][ni], 0, 0, 0);                       \
    __builtin_amdgcn_s_setprio(0)

#define RD(p, imm) (*(const bf16x8*)((p) + (imm)))

template <int MODE>
__global__ __launch_bounds__(512, 4) void gemm2_kernel(
    const u16* __restrict__ A, const u16* __restrict__ Wb,
    const float* __restrict__ b0, const float* __restrict__ b1,
    const float* __restrict__ b2,
    u16* __restrict__ outb, const u16* __restrict__ xres) {
    extern __shared__ char lds[];    // 65536 B

    const int t = threadIdx.x;
    const int w = t >> 6, l = t & 63;
    const int wm = w >> 2, wn = w & 3;

    const int NTN = (MODE == 0) ? 18 : 6;
    const int work = xcd_swz(blockIdx.x, gridDim.x);
    const int mt = work / NTN, nt = work % NTN;   // nt fastest: A L2-reuse in XCD
    const int m0 = mt * 128;
    const int col0 = nt * 128;                    // output column base
    const int widx = (MODE == 0) ? (nt / 6) : 3;
    const int n0w  = (MODE == 0) ? (nt % 6) * 128 : col0;  // weight-row base

    // ---- staging geometry (pre-swizzled source; 128B rows, 8 slots) ----
    const int sr = w * 16 + (l >> 3);            // row 0..127 (this wave: 16 rows)
    const int sc = l & 7;                        // LDS slot this lane fills
    const int schunk = sc ^ (sr & 7);            // global chunk to fetch
    const u16* Asrc = A + (size_t)(m0 + sr) * D_ + schunk * 8;
    const u16* Bsrc = Wb + (size_t)widx * (D_ * D_)
                         + (size_t)(n0w + sr) * D_ + schunk * 8;
    char* const dstA = lds + w * 2048;           // + buf*32768 (+1024 2nd call)
    char* const dstB = lds + 16384 + w * 2048;

    // ---- ds_read geometry (swizzled slot; verified pattern) ----
    const int ck0 = (((l >> 4) ^ (l & 7)) << 4);         // kh0 slot byte
    const int ck1 = ((((l >> 4) + 4) ^ (l & 7)) << 4);   // kh1 slot byte
    const char* aB = lds + (wm * 64 + (l & 15)) * 128;           // +buf +mi*2048
    const char* bB = lds + 16384 + (wn * 32 + (l & 15)) * 128;   // +buf +ni*2048

    f32x4 acc[4][2];
#pragma unroll
    for (int i = 0; i < 4; i++)
#pragma unroll
        for (int j = 0; j < 2; j++) acc[i][j] = (f32x4){0.f, 0.f, 0.f, 0.f};

    // stage K-tile tk into buffer b (per wave: A 2 + B 2 gloads, 16 rows each)
    auto STAGE = [&](int tk, int b) {
        const int ko = tk * 64;                  // element offset along K
        char* da = dstA + b * 32768;
        char* db = dstB + b * 32768;
        gload_lds16(Asrc + ko, da);
        gload_lds16(Asrc + ko + 8 * D_, da + 1024);
        gload_lds16(Bsrc + ko, db);
        gload_lds16(Bsrc + ko + 8 * D_, db + 1024);
    };

    // ---- prologue ----
    STAGE(0, 0);
    __syncthreads();

#pragma unroll
    for (int X = 0; X < NTILES; ++X) {
        const int cb = (X & 1) * 32768;
        if (X + 1 < NTILES) STAGE(X + 1, (X & 1) ^ 1);

        bf16x8 af[4], bf[2];
        // kh0
#pragma unroll
        for (int mi = 0; mi < 4; ++mi) af[mi] = RD(aB, cb + mi * 2048 + ck0);
#pragma unroll
        for (int ni = 0; ni < 2; ++ni) bf[ni] = RD(bB, cb + ni * 2048 + ck0);
        MFMA8(af, bf);
        // kh1
#pragma unroll
        for (int mi = 0; mi < 4; ++mi) af[mi] = RD(aB, cb + mi * 2048 + ck1);
#pragma unroll
        for (int ni = 0; ni < 2; ++ni) bf[ni] = RD(bB, cb + ni * 2048 + ck1);
        MFMA8(af, bf);

        __syncthreads();   // full drain: vmcnt(0)+lgkm(0)+barrier (race-free)
    }

    // ---- epilogue ----
    const int crow0 = m0 + wm * 64 + ((l >> 4) << 2);
    const int ccol0 = col0 + wn * 32 + (l & 15);
    if (MODE == 0) {
        const float* bias = (widx == 0) ? b0 : (widx == 1) ? b1 : b2;
        const int bcol0 = ccol0 - widx * D_;
#pragma unroll
        for (int mi = 0; mi < 4; ++mi)
#pragma unroll
            for (int ni = 0; ni < 2; ++ni) {
                const float bv = bias[bcol0 + ni * 16];
#pragma unroll
                for (int r = 0; r < 4; ++r)
                    outb[(size_t)(crow0 + mi * 16 + r) * NQKV_ + ccol0 + ni * 16] =
                        f2bf(acc[mi][ni][r] + bv);
            }
    } else {
#pragma unroll
        for (int mi = 0; mi < 4; ++mi)
#pragma unroll
            for (int ni = 0; ni < 2; ++ni) {
                const int col = ccol0 + ni * 16;
                const float bv = b0[col];
#pragma unroll
                for (int r = 0; r < 4; ++r) {
                    const size_t idx = (size_t)(crow0 + mi * 16 + r) * D_ + col;
                    outb[idx] = f2bf(acc[mi][ni][r] + bv + bf2f(xres[idx]));
                }
            }
    }
}

// ---------------- local attention: one wave per (m, head-quad) ----------------
__global__ __launch_bounds__(256) void attn_kernel(const u16* __restrict__ QKV,
                                                   const float* __restrict__ bk,
                                                   const float* __restrict__ bv,
                                                   u16* __restrict__ att) {
    const int gw = xcd_swz(blockIdx.x, gridDim.x) * 4 + (threadIdx.x >> 6);
    const int l  = threadIdx.x & 63;
    const int hq = gw % 3;             // head-quad index
    const int m  = gw / 3;
    const int s  = m & (S_ - 1);
    const int col = hq * 256 + l * 4;
    const u16* base = QKV + (size_t)m * NQKV_;

    const u16x4 qv = *(const u16x4*)(base + col);
    float qf[4];
#pragma unroll
    for (int j = 0; j < 4; j++) qf[j] = bf2f(qv[j]);

    float sc[5];
#pragma unroll
    for (int i = 0; i < 5; i++) {
        const int sp = s + i - 2;
        float p;
        if (sp >= 0 && sp < S_) {
            const u16x4 kv = *(const u16x4*)(base + (i - 2) * NQKV_ + D_ + col);
            p = qf[0] * bf2f(kv[0]) + qf[1] * bf2f(kv[1])
              + qf[2] * bf2f(kv[2]) + qf[3] * bf2f(kv[3]);
        } else {
            const float4 kb = *(const float4*)(bk + col);
            p = qf[0] * kb.x + qf[1] * kb.y + qf[2] * kb.z + qf[3] * kb.w;
        }
#pragma unroll
        for (int off = 1; off < 16; off <<= 1) p += __shfl_xor(p, off, 64);
        sc[i] = p * 0.125f;
    }
    float mx = sc[0];
#pragma unroll
    for (int i = 1; i < 5; i++) mx = fmaxf(mx, sc[i]);
    float e[5], sum = 0.f;
#pragma unroll
    for (int i = 0; i < 5; i++) { e[i] = __expf(sc[i] - mx); sum += e[i]; }
    const float inv = 1.f / sum;

    float o[4] = {0.f, 0.f, 0.f, 0.f};
#pragma unroll
    for (int i = 0; i < 5; i++) {
        const float wgt = e[i] * inv;
        const int sp = s + i - 2;
        if (sp >= 0 && sp < S_) {
            const u16x4 vv = *(const u16x4*)(base + (i - 2) * NQKV_ + 2 * D_ + col);
#pragma unroll
            for (int j = 0; j < 4; j++) o[j] += wgt * bf2f(vv[j]);
        } else {
            const float4 vb = *(const float4*)(bv + col);
            o[0] += wgt * vb.x; o[1] += wgt * vb.y;
            o[2] += wgt * vb.z; o[3] += wgt * vb.w;
        }
    }
    u16x4 ov;
#pragma unroll
    for (int j = 0; j < 4; j++) ov[j] = f2bf(o[j]);
    *(u16x4*)(att + (size_t)m * D_ + col) = ov;
}

// ---------------- LayerNorm over rows of 768 (bf16 in, f32 out) ----------------
__global__ __launch_bounds__(256) void ln_kernel(const u16* __restrict__ Yb,
                                                 const float* __restrict__ gamma,
                                                 const float* __restrict__ beta,
                                                 float* __restrict__ out) {
    const int row = blockIdx.x;
    const u16* r = Yb + (size_t)row * D_;
    const int t = threadIdx.x;
    const float v0 = bf2f(r[t]), v1 = bf2f(r[t + 256]), v2 = bf2f(r[t + 512]);
    float s  = v0 + v1 + v2;
    float s2 = v0 * v0 + v1 * v1 + v2 * v2;
#pragma unroll
    for (int off = 32; off > 0; off >>= 1) {
        s  += __shfl_xor(s,  off, 64);
        s2 += __shfl_xor(s2, off, 64);
    }
    __shared__ float red[8];
    const int w = t >> 6, l = t & 63;
    if (l == 0) { red[w] = s; red[4 + w] = s2; }
    __syncthreads();
    s  = red[0] + red[1] + red[2] + red[3];
    s2 = red[4] + red[5] + red[6] + red[7];
    const float mu  = s * (1.f / 768.f);
    const float var = s2 * (1.f / 768.f) - mu * mu;
    const float inv = rsqrtf(var + 1e-5f);
    float* o = out + (size_t)row * D_;
    o[t]       = (v0 - mu) * inv * gamma[t]       + beta[t];
    o[t + 256] = (v1 - mu) * inv * gamma[t + 256] + beta[t + 256];
    o[t + 512] = (v2 - mu) * inv * gamma[t + 512] + beta[t + 512];
}

extern "C" void kernel_launch(void* const* d_in, const int* in_sizes, int n_in,
                              void* d_out, int out_size, void* d_ws, size_t ws_size,
                              hipStream_t stream) {
    const float* x     = (const float*)d_in[0];
    const float* Wq    = (const float*)d_in[1];
    const float* bq    = (const float*)d_in[2];
    const float* Wk    = (const float*)d_in[3];
    const float* bk    = (const float*)d_in[4];
    const float* Wv    = (const float*)d_in[5];
    const float* bv    = (const float*)d_in[6];
    const float* Wo    = (const float*)d_in[7];
    const float* bo    = (const float*)d_in[8];
    const float* gamma = (const float*)d_in[9];
    const float* beta  = (const float*)d_in[10];

    char* ws = (char*)d_ws;
    u16*   Wb  = (u16*)ws;                                  //  4,718,592 B
    u16*   xb  = (u16*)(ws + 4718592);                      // 50,331,648 B (stays live)
    u16*   QKV = (u16*)(ws + 4718592 + 50331648);           // 150,994,944 B
    u16*   yb  = QKV;                                       // reuse after attn
    u16*   att = (u16*)d_out;                               // scratch in d_out

    (void)hipFuncSetAttribute(reinterpret_cast<const void*>(&gemm2_kernel<0>),
                              hipFuncAttributeMaxDynamicSharedMemorySize, 65536);
    (void)hipFuncSetAttribute(reinterpret_cast<const void*>(&gemm2_kernel<1>),
                              hipFuncAttributeMaxDynamicSharedMemorySize, 65536);

    castx_kernel<<<(M_ * D_) / (256 * 4), 256, 0, stream>>>(x, xb);
    wtrans_kernel<<<dim3(24, 24, 4), 256, 0, stream>>>(Wq, Wk, Wv, Wo, Wb);
    gemm2_kernel<0><<<(M_ / 128) * 18, 512, 65536, stream>>>(xb, Wb, bq, bk, bv,
                                                             QKV, nullptr);
    attn_kernel<<<(M_ * 3) / 4, 256, 0, stream>>>(QKV, bk, bv, att);
    gemm2_kernel<1><<<(M_ / 128) * 6, 512, 65536, stream>>>(att, Wb, bo, nullptr, nullptr,
                                                            yb, xb);
    ln_kernel<<<M_, 256, 0, stream>>>(yb, gamma, beta, (float*)d_out);
}

// Round 12
// 291.795 us; speedup vs baseline: 1.0498x; 1.0091x over previous
//
#include <hip/hip_runtime.h>

#define B_  8
#define S_  4096
#define D_  768
#define H_  12
#define M_  (B_ * S_)      // 32768
#define NQKV_ 2304         // 3*D
#define NTILES 12          // 768 / 64

typedef unsigned short u16;
typedef __attribute__((ext_vector_type(4))) float  f32x4;
typedef __attribute__((ext_vector_type(8))) __bf16 bf16x8;
typedef __attribute__((ext_vector_type(4))) u16    u16x4;

#define GAS __attribute__((address_space(1)))
#define LAS __attribute__((address_space(3)))

__device__ __forceinline__ u16 f2bf(float f) {
    unsigned u = __float_as_uint(f);
    u += 0x7FFF + ((u >> 16) & 1);          // round-to-nearest-even
    return (u16)(u >> 16);
}
__device__ __forceinline__ float bf2f(u16 h) {
    return __uint_as_float(((unsigned)h) << 16);
}

__device__ __forceinline__ void gload_lds16(const void* g, void* l) {
    __builtin_amdgcn_global_load_lds((const GAS void*)g, (LAS void*)l, 16, 0, 0);
}

// bijective XCD swizzle (nwg % 8 == 0): each XCD gets a contiguous work chunk
__device__ __forceinline__ int xcd_swz(int bid, int nwg) {
    return (bid & 7) * (nwg >> 3) + (bid >> 3);
}

// ---------------- cast x (f32 -> bf16) ----------------
__global__ __launch_bounds__(256) void castx_kernel(const float* __restrict__ x,
                                                    u16* __restrict__ xb) {
    const int i = blockIdx.x * 256 + threadIdx.x;
    const float4 v = ((const float4*)x)[i];
    u16x4 o;
    o.x = f2bf(v.x); o.y = f2bf(v.y); o.z = f2bf(v.z); o.w = f2bf(v.w);
    ((u16x4*)xb)[i] = o;
}

// ---------------- weight transpose+cast: W[k][n] f32 -> Wb[n][k] bf16 ----------------
__global__ __launch_bounds__(256) void wtrans_kernel(const float* __restrict__ Wq,
                                                     const float* __restrict__ Wk,
                                                     const float* __restrict__ Wv,
                                                     const float* __restrict__ Wo,
                                                     u16* __restrict__ Wb) {
    const float* W = (blockIdx.z == 0) ? Wq : (blockIdx.z == 1) ? Wk
                   : (blockIdx.z == 2) ? Wv : Wo;
    u16* O = Wb + (size_t)blockIdx.z * D_ * D_;
    __shared__ float tile[32][33];
    const int tx = threadIdx.x & 31, ty = threadIdx.x >> 5;  // 32x8
    const int k0 = blockIdx.y * 32, n0 = blockIdx.x * 32;
#pragma unroll
    for (int j = 0; j < 4; j++)
        tile[ty + j * 8][tx] = W[(size_t)(k0 + ty + j * 8) * D_ + n0 + tx];
    __syncthreads();
#pragma unroll
    for (int j = 0; j < 4; j++)
        O[(size_t)(n0 + ty + j * 8) * D_ + k0 + tx] = f2bf(tile[tx][ty + j * 8]);
}

// ====== 128x128 double-buffered bf16 MFMA GEMM — per-wave 64x64, 2 blk/CU ======
// 256 threads = 4 waves (2M x 2N), per-wave C = 64x64 (acc 64 f32), BK=64.
// LDS 64 KiB = 2 buffers x (A 128rows x 128B + B 128rows x 128B).
// Rationale (R11 post-mortem): 40% MfmaUtil == LDS-read-BW bound at per-wave
//   64x32 (42.7 FLOP/elem). 64x64 -> 64 FLOP/elem: reads/block-K-tile 96->64KiB
//   at identical MFMA count.
// Swizzle (VERIFIED, R8/R11: 0 conflicts): LDS slot s of row R holds global
//   16B-chunk s ^ (R&7); staging pre-swizzles the source; reads use
//   slot = (chunkgroup) ^ (l&7).
// Schedule: per K-tile { stage X+1 -> other buf; ds_read+MFMA from current;
//   __syncthreads() } — full drain (no counted-vmcnt race class).  Stall
//   hiding: 2 INDEPENDENT blocks/CU (<=128 regs, launch_bounds(256,2)).

#define MFMA16(AF, BF)                                                       \
    __builtin_amdgcn_s_setprio(1);                                           \
    _Pragma("unroll") for (int mi = 0; mi < 4; ++mi)                         \
        _Pragma("unroll") for (int ni = 0; ni < 4; ++ni)                     \
            acc[mi][ni] = __builtin_amdgcn_mfma_f32_16x16x32_bf16(           \
                AF[mi], BF[ni], acc[mi][ni], 0, 0, 0);                       \
    __builtin_amdgcn_s_setprio(0)

#define RD(p, imm) (*(const bf16x8*)((p) + (imm)))

template <int MODE>
__global__ __launch_bounds__(256, 2) void gemm2_kernel(
    const u16* __restrict__ A, const u16* __restrict__ Wb,
    const float* __restrict__ b0, const float* __restrict__ b1,
    const float* __restrict__ b2,
    u16* __restrict__ outb, const u16* __restrict__ xres) {
    extern __shared__ char lds[];    // 65536 B

    const int t = threadIdx.x;
    const int w = t >> 6, l = t & 63;
    const int wm = w >> 1, wn = w & 1;

    const int NTN = (MODE == 0) ? 18 : 6;
    const int work = xcd_swz(blockIdx.x, gridDim.x);
    const int mt = work / NTN, nt = work % NTN;   // nt fastest: A L2-reuse in XCD
    const int m0 = mt * 128;
    const int col0 = nt * 128;                    // output column base
    const int widx = (MODE == 0) ? (nt / 6) : 3;
    const int n0w  = (MODE == 0) ? (nt % 6) * 128 : col0;  // weight-row base

    // ---- staging geometry (pre-swizzled source; 128B rows, 8 slots) ----
    // wave w stages rows [w*32, w*32+32) via 4 gloads of 8 rows each;
    // lane l: row-in-gload = l>>3, slot = l&7, fetches chunk (l&7)^((l>>3)&7).
    const int srow = w * 32 + (l >> 3);
    const int schunk = (l & 7) ^ ((l >> 3) & 7);
    const u16* Asrc = A + (size_t)(m0 + srow) * D_ + schunk * 8;
    const u16* Bsrc = Wb + (size_t)widx * (D_ * D_)
                         + (size_t)(n0w + srow) * D_ + schunk * 8;
    char* const dstA = lds + w * 4096;            // + buf*32768 + g*1024
    char* const dstB = lds + 16384 + w * 4096;

    // ---- ds_read geometry (swizzled slot; verified pattern) ----
    const int ck0 = (((l >> 4) ^ (l & 7)) << 4);         // kh0 slot byte
    const int ck1 = ((((l >> 4) + 4) ^ (l & 7)) << 4);   // kh1 slot byte
    const char* aB = lds + (wm * 64 + (l & 15)) * 128;           // +buf +mi*2048
    const char* bB = lds + 16384 + (wn * 64 + (l & 15)) * 128;   // +buf +ni*2048

    f32x4 acc[4][4];
#pragma unroll
    for (int i = 0; i < 4; i++)
#pragma unroll
        for (int j = 0; j < 4; j++) acc[i][j] = (f32x4){0.f, 0.f, 0.f, 0.f};

    // stage K-tile tk into buffer b (per wave: 4 A + 4 B gloads, 8 rows each)
    auto STAGE = [&](int tk, int b) {
        const int ko = tk * 64;                  // element offset along K
        char* da = dstA + b * 32768;
        char* db = dstB + b * 32768;
#pragma unroll
        for (int g = 0; g < 4; ++g) {
            gload_lds16(Asrc + ko + g * 8 * D_, da + g * 1024);
            gload_lds16(Bsrc + ko + g * 8 * D_, db + g * 1024);
        }
    };

    // ---- prologue ----
    STAGE(0, 0);
    __syncthreads();

#pragma unroll
    for (int X = 0; X < NTILES; ++X) {
        const int cb = (X & 1) * 32768;
        if (X + 1 < NTILES) STAGE(X + 1, (X & 1) ^ 1);

        bf16x8 af[4], bf[4];
        // kh0
#pragma unroll
        for (int mi = 0; mi < 4; ++mi) af[mi] = RD(aB, cb + mi * 2048 + ck0);
#pragma unroll
        for (int ni = 0; ni < 4; ++ni) bf[ni] = RD(bB, cb + ni * 2048 + ck0);
        MFMA16(af, bf);
        // kh1
#pragma unroll
        for (int mi = 0; mi < 4; ++mi) af[mi] = RD(aB, cb + mi * 2048 + ck1);
#pragma unroll
        for (int ni = 0; ni < 4; ++ni) bf[ni] = RD(bB, cb + ni * 2048 + ck1);
        MFMA16(af, bf);

        __syncthreads();   // full drain: vmcnt(0)+lgkm(0)+barrier (race-free)
    }

    // ---- epilogue ----
    const int crow0 = m0 + wm * 64 + ((l >> 4) << 2);
    const int ccol0 = col0 + wn * 64 + (l & 15);
    if (MODE == 0) {
        const float* bias = (widx == 0) ? b0 : (widx == 1) ? b1 : b2;
        const int bcol0 = ccol0 - widx * D_;
#pragma unroll
        for (int mi = 0; mi < 4; ++mi)
#pragma unroll
            for (int ni = 0; ni < 4; ++ni) {
                const float bv = bias[bcol0 + ni * 16];
#pragma unroll
                for (int r = 0; r < 4; ++r)
                    outb[(size_t)(crow0 + mi * 16 + r) * NQKV_ + ccol0 + ni * 16] =
                        f2bf(acc[mi][ni][r] + bv);
            }
    } else {
#pragma unroll
        for (int mi = 0; mi < 4; ++mi)
#pragma unroll
            for (int ni = 0; ni < 4; ++ni) {
                const int col = ccol0 + ni * 16;
                const float bv = b0[col];
#pragma unroll
                for (int r = 0; r < 4; ++r) {
                    const size_t idx = (size_t)(crow0 + mi * 16 + r) * D_ + col;
                    outb[idx] = f2bf(acc[mi][ni][r] + bv + bf2f(xres[idx]));
                }
            }
    }
}

// ---------------- local attention: one wave per (m, head-quad) ----------------
__global__ __launch_bounds__(256) void attn_kernel(const u16* __restrict__ QKV,
                                                   const float* __restrict__ bk,
                                                   const float* __restrict__ bv,
                                                   u16* __restrict__ att) {
    const int gw = xcd_swz(blockIdx.x, gridDim.x) * 4 + (threadIdx.x >> 6);
    const int l  = threadIdx.x & 63;
    const int hq = gw % 3;             // head-quad index
    const int m  = gw / 3;
    const int s  = m & (S_ - 1);
    const int col = hq * 256 + l * 4;
    const u16* base = QKV + (size_t)m * NQKV_;

    const u16x4 qv = *(const u16x4*)(base + col);
    float qf[4];
#pragma unroll
    for (int j = 0; j < 4; j++) qf[j] = bf2f(qv[j]);

    float sc[5];
#pragma unroll
    for (int i = 0; i < 5; i++) {
        const int sp = s + i - 2;
        float p;
        if (sp >= 0 && sp < S_) {
            const u16x4 kv = *(const u16x4*)(base + (i - 2) * NQKV_ + D_ + col);
            p = qf[0] * bf2f(kv[0]) + qf[1] * bf2f(kv[1])
              + qf[2] * bf2f(kv[2]) + qf[3] * bf2f(kv[3]);
        } else {
            const float4 kb = *(const float4*)(bk + col);
            p = qf[0] * kb.x + qf[1] * kb.y + qf[2] * kb.z + qf[3] * kb.w;
        }
#pragma unroll
        for (int off = 1; off < 16; off <<= 1) p += __shfl_xor(p, off, 64);
        sc[i] = p * 0.125f;
    }
    float mx = sc[0];
#pragma unroll
    for (int i = 1; i < 5; i++) mx = fmaxf(mx, sc[i]);
    float e[5], sum = 0.f;
#pragma unroll
    for (int i = 0; i < 5; i++) { e[i] = __expf(sc[i] - mx); sum += e[i]; }
    const float inv = 1.f / sum;

    float o[4] = {0.f, 0.f, 0.f, 0.f};
#pragma unroll
    for (int i = 0; i < 5; i++) {
        const float wgt = e[i] * inv;
        const int sp = s + i - 2;
        if (sp >= 0 && sp < S_) {
            const u16x4 vv = *(const u16x4*)(base + (i - 2) * NQKV_ + 2 * D_ + col);
#pragma unroll
            for (int j = 0; j < 4; j++) o[j] += wgt * bf2f(vv[j]);
        } else {
            const float4 vb = *(const float4*)(bv + col);
            o[0] += wgt * vb.x; o[1] += wgt * vb.y;
            o[2] += wgt * vb.z; o[3] += wgt * vb.w;
        }
    }
    u16x4 ov;
#pragma unroll
    for (int j = 0; j < 4; j++) ov[j] = f2bf(o[j]);
    *(u16x4*)(att + (size_t)m * D_ + col) = ov;
}

// ---------------- LayerNorm over rows of 768 (bf16 in, f32 out) ----------------
__global__ __launch_bounds__(256) void ln_kernel(const u16* __restrict__ Yb,
                                                 const float* __restrict__ gamma,
                                                 const float* __restrict__ beta,
                                                 float* __restrict__ out) {
    const int row = blockIdx.x;
    const u16* r = Yb + (size_t)row * D_;
    const int t = threadIdx.x;
    const float v0 = bf2f(r[t]), v1 = bf2f(r[t + 256]), v2 = bf2f(r[t + 512]);
    float s  = v0 + v1 + v2;
    float s2 = v0 * v0 + v1 * v1 + v2 * v2;
#pragma unroll
    for (int off = 32; off > 0; off >>= 1) {
        s  += __shfl_xor(s,  off, 64);
        s2 += __shfl_xor(s2, off, 64);
    }
    __shared__ float red[8];
    const int w = t >> 6, l = t & 63;
    if (l == 0) { red[w] = s; red[4 + w] = s2; }
    __syncthreads();
    s  = red[0] + red[1] + red[2] + red[3];
    s2 = red[4] + red[5] + red[6] + red[7];
    const float mu  = s * (1.f / 768.f);
    const float var = s2 * (1.f / 768.f) - mu * mu;
    const float inv = rsqrtf(var + 1e-5f);
    float* o = out + (size_t)row * D_;
    o[t]       = (v0 - mu) * inv * gamma[t]       + beta[t];
    o[t + 256] = (v1 - mu) * inv * gamma[t + 256] + beta[t + 256];
    o[t + 512] = (v2 - mu) * inv * gamma[t + 512] + beta[t + 512];
}

extern "C" void kernel_launch(void* const* d_in, const int* in_sizes, int n_in,
                              void* d_out, int out_size, void* d_ws, size_t ws_size,
                              hipStream_t stream) {
    const float* x     = (const float*)d_in[0];
    const float* Wq    = (const float*)d_in[1];
    const float* bq    = (const float*)d_in[2];
    const float* Wk    = (const float*)d_in[3];
    const float* bk    = (const float*)d_in[4];
    const float* Wv    = (const float*)d_in[5];
    const float* bv    = (const float*)d_in[6];
    const float* Wo    = (const float*)d_in[7];
    const float* bo    = (const float*)d_in[8];
    const float* gamma = (const float*)d_in[9];
    const float* beta  = (const float*)d_in[10];

    char* ws = (char*)d_ws;
    u16*   Wb  = (u16*)ws;                                  //  4,718,592 B
    u16*   xb  = (u16*)(ws + 4718592);                      // 50,331,648 B (stays live)
    u16*   QKV = (u16*)(ws + 4718592 + 50331648);           // 150,994,944 B
    u16*   yb  = QKV;                                       // reuse after attn
    u16*   att = (u16*)d_out;                               // scratch in d_out

    (void)hipFuncSetAttribute(reinterpret_cast<const void*>(&gemm2_kernel<0>),
                              hipFuncAttributeMaxDynamicSharedMemorySize, 65536);
    (void)hipFuncSetAttribute(reinterpret_cast<const void*>(&gemm2_kernel<1>),
                              hipFuncAttributeMaxDynamicSharedMemorySize, 65536);

    castx_kernel<<<(M_ * D_) / (256 * 4), 256, 0, stream>>>(x, xb);
    wtrans_kernel<<<dim3(24, 24, 4), 256, 0, stream>>>(Wq, Wk, Wv, Wo, Wb);
    gemm2_kernel<0><<<(M_ / 128) * 18, 256, 65536, stream>>>(xb, Wb, bq, bk, bv,
                                                             QKV, nullptr);
    attn_kernel<<<(M_ * 3) / 4, 256, 0, stream>>>(QKV, bk, bv, att);
    gemm2_kernel<1><<<(M_ / 128) * 6, 256, 65536, stream>>>(att, Wb, bo, nullptr, nullptr,
                                                            yb, xb);
    ln_kernel<<<M_, 256, 0, stream>>>(yb, gamma, beta, (float*)d_out);
}